// Round 1
// baseline (1101.938 us; speedup 1.0000x reference)
//
#include <hip/hip_runtime.h>
#include <cstdint>
#include <cstddef>

// Problem constants
// B=8, C=512, H=8, d=64, HW=32, N=N1=1024
// ws float offsets:
//   yp   @ 0        (4M floats)   -> reused as qb after LN
//   yn   @ 4194304  (4M floats)   -> reused as att after kv GEMM
//   kv   @ 8388608  (8M floats)   -> reused as pj after attention
//   pooled @ 16777216 (4096 floats), kvals (int) right after

// ---------------------------------------------------------------------------
// Multi-scale pooling: yp = sum_{k in 3,5,7} (avgpool_k + maxpool_k), stride 1,
// count_include_pad avg (divide by k*k), -inf-pad max (valid-only max).
__global__ __launch_bounds__(256) void pool_kernel(const float* __restrict__ y,
                                                   float* __restrict__ yp) {
    __shared__ float plane[1024];
    const int bc = blockIdx.x;           // b*512 + c
    const int t = threadIdx.x;
    const float* src = y + (size_t)bc * 1024;
    *reinterpret_cast<float4*>(&plane[t * 4]) =
        reinterpret_cast<const float4*>(src)[t];
    __syncthreads();
#pragma unroll
    for (int qq = 0; qq < 4; qq++) {
        const int p = t + qq * 256;
        const int i = p >> 5, j = p & 31;
        float s3 = 0.f, s5 = 0.f, s7 = 0.f;
        float m3 = -3.402823466e38f, m5 = m3, m7 = m3;
        for (int di = -3; di <= 3; di++) {
            const int ii = i + di;
            if (ii < 0 || ii > 31) continue;
            for (int dj = -3; dj <= 3; dj++) {
                const int jj = j + dj;
                if (jj < 0 || jj > 31) continue;
                const float v = plane[(ii << 5) + jj];
                const int adi = di < 0 ? -di : di;
                const int adj = dj < 0 ? -dj : dj;
                const int rr = adi > adj ? adi : adj;
                s7 += v; m7 = fmaxf(m7, v);
                if (rr <= 2) { s5 += v; m5 = fmaxf(m5, v); }
                if (rr <= 1) { s3 += v; m3 = fmaxf(m3, v); }
            }
        }
        yp[(size_t)bc * 1024 + p] =
            s3 * (1.f / 9.f) + s5 * (1.f / 25.f) + s7 * (1.f / 49.f) + m3 + m5 + m7;
    }
}

// ---------------------------------------------------------------------------
__device__ __forceinline__ float block_sum256(float v, volatile float* scr) {
#pragma unroll
    for (int o = 32; o > 0; o >>= 1) v += __shfl_xor(v, o, 64);
    const int t = threadIdx.x;
    __syncthreads();                 // protect scr from previous use
    if ((t & 63) == 0) scr[t >> 6] = v;
    __syncthreads();
    return scr[0] + scr[1] + scr[2] + scr[3];
}

// LayerNorm over channels (512) per (b, n) row. yp is (b, c, n); yn is (b, n, c).
__global__ __launch_bounds__(256) void ln_kernel(const float* __restrict__ yp,
                                                 const float* __restrict__ g,
                                                 const float* __restrict__ bt,
                                                 float* __restrict__ yn) {
    __shared__ float scr[4];
    const int blk = blockIdx.x;           // b*1024 + n
    const int b = blk >> 10, n = blk & 1023;
    const int t = threadIdx.x;
    const float* base = yp + (size_t)b * 512 * 1024 + n;
    const float v0 = base[(size_t)t * 1024];
    const float v1 = base[(size_t)(t + 256) * 1024];
    const float s = block_sum256(v0 + v1, scr);
    const float mu = s * (1.f / 512.f);
    const float d0 = v0 - mu, d1 = v1 - mu;
    const float s2 = block_sum256(d0 * d0 + d1 * d1, scr);
    const float rs = rsqrtf(s2 * (1.f / 512.f) + 1e-5f);
    float* o = yn + (size_t)blk * 512;
    o[t] = d0 * rs * g[t] + bt[t];
    o[t + 256] = d1 * rs * g[t + 256] + bt[t + 256];
}

// ---------------------------------------------------------------------------
// Global average pool of x over spatial: pooled[b][c]
__global__ __launch_bounds__(256) void pooled_kernel(const float* __restrict__ x,
                                                     float* __restrict__ pooled) {
    __shared__ float scr[4];
    const int bc = blockIdx.x, t = threadIdx.x;
    const float4 v = reinterpret_cast<const float4*>(x + (size_t)bc * 1024)[t];
    const float s = block_sum256(v.x + v.y + v.z + v.w, scr);
    if (t == 0) pooled[bc] = s * (1.f / 1024.f);
}

// Dynamic-k MLP: relu(pooled @ w1^T + b1) @ w2^T + b2 -> softmax -> kvals
__global__ __launch_bounds__(128) void mlp_kernel(const float* __restrict__ pooled,
                                                  const float* __restrict__ w1,
                                                  const float* __restrict__ b1,
                                                  const float* __restrict__ w2,
                                                  const float* __restrict__ b2,
                                                  int* __restrict__ kvals) {
    __shared__ float pl[512];
    __shared__ float h1[128];
    __shared__ float lg[8];
    const int b = blockIdx.x, t = threadIdx.x;   // 128 threads
#pragma unroll
    for (int i = 0; i < 4; i++) pl[t + i * 128] = pooled[b * 512 + t + i * 128];
    __syncthreads();
    float acc = b1[t];
    for (int i = 0; i < 512; i++) acc = fmaf(pl[i], w1[t * 512 + i], acc);
    h1[t] = fmaxf(acc, 0.f);
    __syncthreads();
    if (t < 8) {
        float a = b2[t];
        for (int i = 0; i < 128; i++) a = fmaf(h1[i], w2[t * 128 + i], a);
        lg[t] = a;
    }
    __syncthreads();
    if (t == 0) {
        float m = lg[0];
#pragma unroll
        for (int h = 1; h < 8; h++) m = fmaxf(m, lg[h]);
        float e[8], s = 0.f;
#pragma unroll
        for (int h = 0; h < 8; h++) { e[h] = expf(lg[h] - m); s += e[h]; }
#pragma unroll
        for (int h = 0; h < 8; h++) {
            const float p = e[h] / s;
            int kv = (int)floorf(p * 1024.f);
            kv = kv < 1 ? 1 : (kv > 1024 ? 1024 : kv);
            kvals[b * 8 + h] = kv;
        }
    }
}

// ---------------------------------------------------------------------------
// fp32 GEMM: C[M,Nout] = A[M,512] @ W[Nout,512]^T (+bias)
// XLAYOUT=1: A is x-layout (per-batch channel-major: A[m][k] = x[b][k][nsp])
template <int XLAYOUT, int HASBIAS>
__global__ __launch_bounds__(256) void gemm64(const float* __restrict__ A,
                                              const float* __restrict__ W,
                                              const float* __restrict__ bias,
                                              float* __restrict__ Cout, int Nout) {
    constexpr int K = 512;
    __shared__ float As[16][64];
    __shared__ float Ws[16][64];
    const int n0 = blockIdx.x * 64;
    const int m0 = blockIdx.y * 64;
    const int t = threadIdx.x;
    const int tm = t >> 4, tn = t & 15;
    float acc[4][4] = {};
    const float* aBase;
    if (XLAYOUT) {
        aBase = A + (size_t)(m0 >> 10) * K * 1024 + (m0 & 1023);
    } else {
        aBase = A + (size_t)m0 * K;
    }
    const float* wBase = W + (size_t)n0 * K;
    for (int k0 = 0; k0 < K; k0 += 16) {
        if (XLAYOUT) {
            const int kk = t >> 4, mm = (t & 15) * 4;
            const float4 v = *reinterpret_cast<const float4*>(
                &aBase[(size_t)(k0 + kk) * 1024 + mm]);
            *reinterpret_cast<float4*>(&As[kk][mm]) = v;
        } else {
            const int mm = t >> 2, kb = (t & 3) * 4;
            const float4 v =
                *reinterpret_cast<const float4*>(&aBase[(size_t)mm * K + k0 + kb]);
            As[kb + 0][mm] = v.x; As[kb + 1][mm] = v.y;
            As[kb + 2][mm] = v.z; As[kb + 3][mm] = v.w;
        }
        {
            const int mm = t >> 2, kb = (t & 3) * 4;
            const float4 v =
                *reinterpret_cast<const float4*>(&wBase[(size_t)mm * K + k0 + kb]);
            Ws[kb + 0][mm] = v.x; Ws[kb + 1][mm] = v.y;
            Ws[kb + 2][mm] = v.z; Ws[kb + 3][mm] = v.w;
        }
        __syncthreads();
#pragma unroll
        for (int kk = 0; kk < 16; kk++) {
            const float4 av = *reinterpret_cast<float4*>(&As[kk][tm * 4]);
            const float4 bv = *reinterpret_cast<float4*>(&Ws[kk][tn * 4]);
            const float a_[4] = {av.x, av.y, av.z, av.w};
            const float b_[4] = {bv.x, bv.y, bv.z, bv.w};
#pragma unroll
            for (int i = 0; i < 4; i++)
#pragma unroll
                for (int j = 0; j < 4; j++)
                    acc[i][j] = fmaf(a_[i], b_[j], acc[i][j]);
        }
        __syncthreads();
    }
#pragma unroll
    for (int i = 0; i < 4; i++) {
        float4 o;
        o.x = acc[i][0]; o.y = acc[i][1]; o.z = acc[i][2]; o.w = acc[i][3];
        if (HASBIAS) {
            o.x += bias[n0 + tn * 4 + 0];
            o.y += bias[n0 + tn * 4 + 1];
            o.z += bias[n0 + tn * 4 + 2];
            o.w += bias[n0 + tn * 4 + 3];
        }
        *reinterpret_cast<float4*>(
            &Cout[(size_t)(m0 + tm * 4 + i) * Nout + n0 + tn * 4]) = o;
    }
}

// ---------------------------------------------------------------------------
__device__ __forceinline__ unsigned xform(float f) {
    const unsigned u = __float_as_uint(f);
    return (u & 0x80000000u) ? ~u : (u | 0x80000000u);
}
__device__ __forceinline__ float unxform(unsigned k) {
    const unsigned u = (k & 0x80000000u) ? (k & 0x7fffffffu) : ~k;
    return __uint_as_float(u);
}

// Fused attention: per block = one (b,h) and 8 query rows.
// QK^T -> exact k-th-largest radix select -> softmax(attn*mask) weights -> PV.
__global__ __launch_bounds__(256) void attn_kernel(const float* __restrict__ qb,
                                                   const float* __restrict__ kvb,
                                                   const int* __restrict__ kvals,
                                                   const float* __restrict__ temp,
                                                   float* __restrict__ outa) {
    __shared__ float qs[8][64];
    __shared__ float attn[8][1024];
    __shared__ int hist[256];
    __shared__ float fscr[8];
    __shared__ int s_bin, s_kk;
    __shared__ float pvscr[256];

    const int blk = blockIdx.x;       // 8192
    const int rblk = blk & 127;
    const int bh = blk >> 7;
    const int b = bh >> 3, h = bh & 7;
    const int n0 = rblk * 8;
    const int t = threadIdx.x;
    const int lane = t & 63, wid = t >> 6;

#pragma unroll
    for (int i = 0; i < 2; i++) {
        const int idx = t + i * 256;
        const int r = idx >> 6, dd = idx & 63;
        qs[r][dd] = qb[((size_t)(b * 1024 + n0 + r)) * 512 + h * 64 + dd];
    }
    const float tempv = temp[h];
    const int kval = kvals[b * 8 + h];
    __syncthreads();

    // ---- phase 1: logits ----
    {
        const float* kb = kvb + (size_t)b * 1024 * 1024 + h * 64;
        float acc[4][8];
#pragma unroll
        for (int c = 0; c < 4; c++)
#pragma unroll
            for (int r = 0; r < 8; r++) acc[c][r] = 0.f;
#pragma unroll
        for (int d4 = 0; d4 < 16; d4++) {
            float4 qv[8];
#pragma unroll
            for (int r = 0; r < 8; r++)
                qv[r] = *reinterpret_cast<const float4*>(&qs[r][d4 * 4]);
#pragma unroll
            for (int c = 0; c < 4; c++) {
                const int m = c * 256 + t;
                const float4 kv4 = *reinterpret_cast<const float4*>(
                    &kb[(size_t)m * 1024 + d4 * 4]);
#pragma unroll
                for (int r = 0; r < 8; r++) {
                    acc[c][r] = fmaf(kv4.x, qv[r].x, acc[c][r]);
                    acc[c][r] = fmaf(kv4.y, qv[r].y, acc[c][r]);
                    acc[c][r] = fmaf(kv4.z, qv[r].z, acc[c][r]);
                    acc[c][r] = fmaf(kv4.w, qv[r].w, acc[c][r]);
                }
            }
        }
#pragma unroll
        for (int c = 0; c < 4; c++)
#pragma unroll
            for (int r = 0; r < 8; r++) attn[r][c * 256 + t] = acc[c][r] * tempv;
    }
    __syncthreads();

    // ---- phase 2+3 per row: radix-select threshold, masked softmax weights ----
    for (int r = 0; r < 8; r++) {
        float4 a4 = *reinterpret_cast<float4*>(&attn[r][t * 4]);
        const unsigned key[4] = {xform(a4.x), xform(a4.y), xform(a4.z), xform(a4.w)};
        unsigned prefix = 0;
        int kk = kval;
#pragma unroll
        for (int by = 3; by >= 0; by--) {
            hist[t] = 0;
            __syncthreads();
#pragma unroll
            for (int q = 0; q < 4; q++) {
                const unsigned hi = (by == 3) ? 0u : (key[q] >> ((by + 1) * 8));
                if (hi == prefix) atomicAdd(&hist[(key[q] >> (by * 8)) & 255], 1);
            }
            __syncthreads();
            if (t < 64) {
                const int c0 = hist[t * 4], c1 = hist[t * 4 + 1];
                const int c2 = hist[t * 4 + 2], c3 = hist[t * 4 + 3];
                int suf = c0 + c1 + c2 + c3;
#pragma unroll
                for (int off = 1; off < 64; off <<= 1) {
                    const int o = __shfl_down(suf, off, 64);
                    if (t + off < 64) suf += o;
                }
                const int nxtr = __shfl_down(suf, 1, 64);
                const int nxt = (t == 63) ? 0 : nxtr;
                if (suf >= kk && nxt < kk) {
                    int bin, rem;
                    if (nxt + c3 >= kk) { bin = t * 4 + 3; rem = kk - nxt; }
                    else if (nxt + c3 + c2 >= kk) { bin = t * 4 + 2; rem = kk - nxt - c3; }
                    else if (nxt + c3 + c2 + c1 >= kk) { bin = t * 4 + 1; rem = kk - nxt - c3 - c2; }
                    else { bin = t * 4; rem = kk - nxt - c3 - c2 - c1; }
                    s_bin = bin; s_kk = rem;
                }
            }
            __syncthreads();
            prefix = (prefix << 8) | (unsigned)s_bin;
            kk = s_kk;
        }
        const float thr = unxform(prefix);
        const float v0 = (a4.x >= thr) ? a4.x : 0.f;
        const float v1 = (a4.y >= thr) ? a4.y : 0.f;
        const float v2 = (a4.z >= thr) ? a4.z : 0.f;
        const float v3 = (a4.w >= thr) ? a4.w : 0.f;
        float mx = fmaxf(fmaxf(v0, v1), fmaxf(v2, v3));
#pragma unroll
        for (int off = 32; off; off >>= 1) mx = fmaxf(mx, __shfl_xor(mx, off, 64));
        if (lane == 0) fscr[wid] = mx;
        __syncthreads();
        mx = fmaxf(fmaxf(fscr[0], fscr[1]), fmaxf(fscr[2], fscr[3]));
        const float w0 = __expf(v0 - mx), w1 = __expf(v1 - mx);
        const float w2 = __expf(v2 - mx), w3 = __expf(v3 - mx);
        float s = w0 + w1 + w2 + w3;
#pragma unroll
        for (int off = 32; off; off >>= 1) s += __shfl_xor(s, off, 64);
        if (lane == 0) fscr[4 + wid] = s;
        __syncthreads();
        const float den = fscr[4] + fscr[5] + fscr[6] + fscr[7];
        const float inv = 1.f / den;
        a4.x = w0 * inv; a4.y = w1 * inv; a4.z = w2 * inv; a4.w = w3 * inv;
        *reinterpret_cast<float4*>(&attn[r][t * 4]) = a4;
        __syncthreads();
    }

    // ---- phase 4: PV ----
    {
        const float* vb = kvb + (size_t)b * 1024 * 1024 + 512 + h * 64;
        const int dd = t & 63, qt = t >> 6;
        float acc[8];
#pragma unroll
        for (int r = 0; r < 8; r++) acc[r] = 0.f;
        for (int mc = 0; mc < 64; mc++) {
            const int mb = (qt * 64 + mc) * 4;
            float4 w4[8];
#pragma unroll
            for (int r = 0; r < 8; r++)
                w4[r] = *reinterpret_cast<float4*>(&attn[r][mb]);
            const float vv0 = vb[(size_t)(mb + 0) * 1024 + dd];
            const float vv1 = vb[(size_t)(mb + 1) * 1024 + dd];
            const float vv2 = vb[(size_t)(mb + 2) * 1024 + dd];
            const float vv3 = vb[(size_t)(mb + 3) * 1024 + dd];
#pragma unroll
            for (int r = 0; r < 8; r++) {
                acc[r] = fmaf(w4[r].x, vv0, acc[r]);
                acc[r] = fmaf(w4[r].y, vv1, acc[r]);
                acc[r] = fmaf(w4[r].z, vv2, acc[r]);
                acc[r] = fmaf(w4[r].w, vv3, acc[r]);
            }
        }
        for (int r = 0; r < 8; r++) {
            pvscr[t] = acc[r];
            __syncthreads();
            if (t < 64) {
                const float s =
                    pvscr[t] + pvscr[64 + t] + pvscr[128 + t] + pvscr[192 + t];
                outa[((size_t)(b * 1024 + n0 + r)) * 512 + h * 64 + t] = s;
            }
            __syncthreads();
        }
    }
}

// ---------------------------------------------------------------------------
// (b, nsp, ch) -> (b, ch, nsp)
__global__ __launch_bounds__(256) void transpose_out(const float* __restrict__ P,
                                                     float* __restrict__ out) {
    __shared__ float tile[32][33];
    const int blk = blockIdx.x;
    const int tcH = blk & 15;
    const int tnH = (blk >> 4) & 31;
    const int b = blk >> 9;
    const int ch0 = tcH * 32, n0 = tnH * 32;
    const int t = threadIdx.x;
    const int c = t & 31, rr = t >> 5;
#pragma unroll
    for (int it = 0; it < 4; it++) {
        const int r = rr + it * 8;
        tile[r][c] = P[((size_t)(b * 1024 + n0 + r)) * 512 + ch0 + c];
    }
    __syncthreads();
#pragma unroll
    for (int it = 0; it < 4; it++) {
        const int r = rr + it * 8;
        out[((size_t)(b * 512 + ch0 + r)) * 1024 + n0 + c] = tile[c][r];
    }
}

// ---------------------------------------------------------------------------
extern "C" void kernel_launch(void* const* d_in, const int* in_sizes, int n_in,
                              void* d_out, int out_size, void* d_ws, size_t ws_size,
                              hipStream_t stream) {
    const float* x = (const float*)d_in[0];
    const float* y = (const float*)d_in[1];
    const float* temp = (const float*)d_in[2];
    const float* q_w = (const float*)d_in[3];
    const float* kv_w = (const float*)d_in[4];
    const float* proj_w = (const float*)d_in[5];
    const float* proj_b = (const float*)d_in[6];
    const float* dk_w1 = (const float*)d_in[7];
    const float* dk_b1 = (const float*)d_in[8];
    const float* dk_w2 = (const float*)d_in[9];
    const float* dk_b2 = (const float*)d_in[10];
    const float* ln_g = (const float*)d_in[11];
    const float* ln_b = (const float*)d_in[12];
    float* out = (float*)d_out;
    float* ws = (float*)d_ws;

    float* yp = ws + 0;
    float* yn = ws + 4194304;
    float* kv = ws + 8388608;
    float* qb = ws + 0;          // reuse yp
    float* att = ws + 4194304;   // reuse yn
    float* pj = ws + 8388608;    // reuse kv
    float* pooled = ws + 16777216;
    int* kvals = (int*)(ws + 16777216 + 4096);

    pool_kernel<<<4096, 256, 0, stream>>>(y, yp);
    ln_kernel<<<8192, 256, 0, stream>>>(yp, ln_g, ln_b, yn);
    pooled_kernel<<<4096, 256, 0, stream>>>(x, pooled);
    mlp_kernel<<<8, 128, 0, stream>>>(pooled, dk_w1, dk_b1, dk_w2, dk_b2, kvals);
    gemm64<1, 0><<<dim3(8, 128), 256, 0, stream>>>(x, q_w, nullptr, qb, 512);
    gemm64<0, 0><<<dim3(16, 128), 256, 0, stream>>>(yn, kv_w, nullptr, kv, 1024);
    attn_kernel<<<8192, 256, 0, stream>>>(qb, kv, kvals, temp, att);
    gemm64<0, 1><<<dim3(8, 128), 256, 0, stream>>>(att, proj_w, proj_b, pj, 512);
    transpose_out<<<4096, 256, 0, stream>>>(pj, out);
}

// Round 2
// 606.698 us; speedup vs baseline: 1.8163x; 1.8163x over previous
//
#include <hip/hip_runtime.h>
#include <cstdint>
#include <cstddef>

// B=8, C=512, H=8, d=64, HW=32, N=N1=1024
// ws float offsets:
//   yp    @0        (4M f32)  dead after ln
//   yn    @4M       (4M f32)  dead after kv gemm
//   kvf   @8M       (8M f32)  dead after reshape
//   qbf   @0        (4M bf16 = 2M f32 slots)   written by gemm_q (after ln)
//   kbf   @2M       (4M bf16)                  written by reshape
//   vtbf  @4M       (4M bf16)                  written by reshape
//   att   @8M       (4M f32)                   written by attn
//   pj    @12M      (4M f32)                   written by proj gemm
//   pooled @16M, kvals after

typedef short bf16x8 __attribute__((ext_vector_type(8)));
typedef float f32x4 __attribute__((ext_vector_type(4)));

__device__ __forceinline__ unsigned short f2bf(float f) {
    unsigned u = __float_as_uint(f);
    u = (u + 0x7fffu + ((u >> 16) & 1u)) >> 16;
    return (unsigned short)u;
}
__device__ __forceinline__ unsigned xform_u(unsigned u) {
    return (u & 0x80000000u) ? ~u : (u | 0x80000000u);
}
__device__ __forceinline__ float unxform_f(unsigned k) {
    const unsigned u = (k & 0x80000000u) ? (k & 0x7fffffffu) : ~k;
    return __uint_as_float(u);
}

// ---------------------------------------------------------------------------
__global__ __launch_bounds__(256) void pool_kernel(const float* __restrict__ y,
                                                   float* __restrict__ yp) {
    __shared__ float plane[1024];
    const int bc = blockIdx.x;           // b*512 + c
    const int t = threadIdx.x;
    const float* src = y + (size_t)bc * 1024;
    *reinterpret_cast<float4*>(&plane[t * 4]) =
        reinterpret_cast<const float4*>(src)[t];
    __syncthreads();
#pragma unroll
    for (int qq = 0; qq < 4; qq++) {
        const int p = t + qq * 256;
        const int i = p >> 5, j = p & 31;
        float s3 = 0.f, s5 = 0.f, s7 = 0.f;
        float m3 = -3.402823466e38f, m5 = m3, m7 = m3;
        for (int di = -3; di <= 3; di++) {
            const int ii = i + di;
            if (ii < 0 || ii > 31) continue;
            for (int dj = -3; dj <= 3; dj++) {
                const int jj = j + dj;
                if (jj < 0 || jj > 31) continue;
                const float v = plane[(ii << 5) + jj];
                const int adi = di < 0 ? -di : di;
                const int adj = dj < 0 ? -dj : dj;
                const int rr = adi > adj ? adi : adj;
                s7 += v; m7 = fmaxf(m7, v);
                if (rr <= 2) { s5 += v; m5 = fmaxf(m5, v); }
                if (rr <= 1) { s3 += v; m3 = fmaxf(m3, v); }
            }
        }
        yp[(size_t)bc * 1024 + p] =
            s3 * (1.f / 9.f) + s5 * (1.f / 25.f) + s7 * (1.f / 49.f) + m3 + m5 + m7;
    }
}

// ---------------------------------------------------------------------------
__device__ __forceinline__ float block_sum256(float v, volatile float* scr) {
#pragma unroll
    for (int o = 32; o > 0; o >>= 1) v += __shfl_xor(v, o, 64);
    const int t = threadIdx.x;
    __syncthreads();
    if ((t & 63) == 0) scr[t >> 6] = v;
    __syncthreads();
    return scr[0] + scr[1] + scr[2] + scr[3];
}

__global__ __launch_bounds__(256) void ln_kernel(const float* __restrict__ yp,
                                                 const float* __restrict__ g,
                                                 const float* __restrict__ bt,
                                                 float* __restrict__ yn) {
    __shared__ float scr[4];
    const int blk = blockIdx.x;           // b*1024 + n
    const int b = blk >> 10, n = blk & 1023;
    const int t = threadIdx.x;
    const float* base = yp + (size_t)b * 512 * 1024 + n;
    const float v0 = base[(size_t)t * 1024];
    const float v1 = base[(size_t)(t + 256) * 1024];
    const float s = block_sum256(v0 + v1, scr);
    const float mu = s * (1.f / 512.f);
    const float d0 = v0 - mu, d1 = v1 - mu;
    const float s2 = block_sum256(d0 * d0 + d1 * d1, scr);
    const float rs = rsqrtf(s2 * (1.f / 512.f) + 1e-5f);
    float* o = yn + (size_t)blk * 512;
    o[t] = d0 * rs * g[t] + bt[t];
    o[t + 256] = d1 * rs * g[t + 256] + bt[t + 256];
}

// ---------------------------------------------------------------------------
__global__ __launch_bounds__(256) void pooled_kernel(const float* __restrict__ x,
                                                     float* __restrict__ pooled) {
    __shared__ float scr[4];
    const int bc = blockIdx.x, t = threadIdx.x;
    const float4 v = reinterpret_cast<const float4*>(x + (size_t)bc * 1024)[t];
    const float s = block_sum256(v.x + v.y + v.z + v.w, scr);
    if (t == 0) pooled[bc] = s * (1.f / 1024.f);
}

__global__ __launch_bounds__(128) void mlp_kernel(const float* __restrict__ pooled,
                                                  const float* __restrict__ w1,
                                                  const float* __restrict__ b1,
                                                  const float* __restrict__ w2,
                                                  const float* __restrict__ b2,
                                                  int* __restrict__ kvals) {
    __shared__ float pl[512];
    __shared__ float h1[128];
    __shared__ float lg[8];
    const int b = blockIdx.x, t = threadIdx.x;
#pragma unroll
    for (int i = 0; i < 4; i++) pl[t + i * 128] = pooled[b * 512 + t + i * 128];
    __syncthreads();
    float acc = b1[t];
    for (int i = 0; i < 512; i++) acc = fmaf(pl[i], w1[t * 512 + i], acc);
    h1[t] = fmaxf(acc, 0.f);
    __syncthreads();
    if (t < 8) {
        float a = b2[t];
        for (int i = 0; i < 128; i++) a = fmaf(h1[i], w2[t * 128 + i], a);
        lg[t] = a;
    }
    __syncthreads();
    if (t == 0) {
        float m = lg[0];
#pragma unroll
        for (int h = 1; h < 8; h++) m = fmaxf(m, lg[h]);
        float e[8], s = 0.f;
#pragma unroll
        for (int h = 0; h < 8; h++) { e[h] = expf(lg[h] - m); s += e[h]; }
#pragma unroll
        for (int h = 0; h < 8; h++) {
            const float p = e[h] / s;
            int kv = (int)floorf(p * 1024.f);
            kv = kv < 1 ? 1 : (kv > 1024 ? 1024 : kv);
            kvals[b * 8 + h] = kv;
        }
    }
}

// ---------------------------------------------------------------------------
// fp32 GEMM: C[M,Nout] = A[M,512] @ W[Nout,512]^T (+bias). OB=1 -> bf16 output.
template <int XLAYOUT, int HASBIAS, int OB>
__global__ __launch_bounds__(256) void gemm64(const float* __restrict__ A,
                                              const float* __restrict__ W,
                                              const float* __restrict__ bias,
                                              void* __restrict__ CoutV, int Nout) {
    constexpr int K = 512;
    __shared__ float As[16][64];
    __shared__ float Ws[16][64];
    const int n0 = blockIdx.x * 64;
    const int m0 = blockIdx.y * 64;
    const int t = threadIdx.x;
    const int tm = t >> 4, tn = t & 15;
    float acc[4][4] = {};
    const float* aBase;
    if (XLAYOUT) {
        aBase = A + (size_t)(m0 >> 10) * K * 1024 + (m0 & 1023);
    } else {
        aBase = A + (size_t)m0 * K;
    }
    const float* wBase = W + (size_t)n0 * K;
    for (int k0 = 0; k0 < K; k0 += 16) {
        if (XLAYOUT) {
            const int kk = t >> 4, mm = (t & 15) * 4;
            const float4 v = *reinterpret_cast<const float4*>(
                &aBase[(size_t)(k0 + kk) * 1024 + mm]);
            *reinterpret_cast<float4*>(&As[kk][mm]) = v;
        } else {
            const int mm = t >> 2, kb = (t & 3) * 4;
            const float4 v =
                *reinterpret_cast<const float4*>(&aBase[(size_t)mm * K + k0 + kb]);
            As[kb + 0][mm] = v.x; As[kb + 1][mm] = v.y;
            As[kb + 2][mm] = v.z; As[kb + 3][mm] = v.w;
        }
        {
            const int mm = t >> 2, kb = (t & 3) * 4;
            const float4 v =
                *reinterpret_cast<const float4*>(&wBase[(size_t)mm * K + k0 + kb]);
            Ws[kb + 0][mm] = v.x; Ws[kb + 1][mm] = v.y;
            Ws[kb + 2][mm] = v.z; Ws[kb + 3][mm] = v.w;
        }
        __syncthreads();
#pragma unroll
        for (int kk = 0; kk < 16; kk++) {
            const float4 av = *reinterpret_cast<float4*>(&As[kk][tm * 4]);
            const float4 bv = *reinterpret_cast<float4*>(&Ws[kk][tn * 4]);
            const float a_[4] = {av.x, av.y, av.z, av.w};
            const float b_[4] = {bv.x, bv.y, bv.z, bv.w};
#pragma unroll
            for (int i = 0; i < 4; i++)
#pragma unroll
                for (int j = 0; j < 4; j++)
                    acc[i][j] = fmaf(a_[i], b_[j], acc[i][j]);
        }
        __syncthreads();
    }
#pragma unroll
    for (int i = 0; i < 4; i++) {
        float o[4];
#pragma unroll
        for (int j = 0; j < 4; j++) {
            o[j] = acc[i][j];
            if (HASBIAS) o[j] += bias[n0 + tn * 4 + j];
        }
        const size_t row = (size_t)(m0 + tm * 4 + i);
        if (OB) {
            ushort4 o16;
            o16.x = f2bf(o[0]); o16.y = f2bf(o[1]);
            o16.z = f2bf(o[2]); o16.w = f2bf(o[3]);
            *reinterpret_cast<ushort4*>(
                &((unsigned short*)CoutV)[row * Nout + n0 + tn * 4]) = o16;
        } else {
            float4 of; of.x = o[0]; of.y = o[1]; of.z = o[2]; of.w = o[3];
            *reinterpret_cast<float4*>(
                &((float*)CoutV)[row * Nout + n0 + tn * 4]) = of;
        }
    }
}

// ---------------------------------------------------------------------------
// kv fp32 [b][n][1024] -> kbf[bh][n][64] bf16 and vtbf[bh][64][n] bf16
__global__ __launch_bounds__(256) void reshape_kv(const float* __restrict__ kvf,
                                                  unsigned short* __restrict__ kbf,
                                                  unsigned short* __restrict__ vtbf) {
    const int blk = blockIdx.x;       // 512: bh*8 + seg
    const int bh = blk >> 3, seg = blk & 7;
    const int b = bh >> 3, h = bh & 7;
    const int t = threadIdx.x;
    // K part: 128 n x 64 d per block
#pragma unroll 4
    for (int i = 0; i < 32; i++) {
        const int idx = i * 256 + t;         // 8192 = 128n * 64d
        const int nl = idx >> 6, d = idx & 63;
        const int n = seg * 128 + nl;
        const float v = kvf[((size_t)(b * 1024 + n)) * 1024 + h * 64 + d];
        kbf[((size_t)bh * 1024 + n) * 64 + d] = f2bf(v);
    }
    // V part (transposed): 64 d x 128 n per block
#pragma unroll 4
    for (int i = 0; i < 32; i++) {
        const int idx = i * 256 + t;         // 8192 = 64d * 128n
        const int d = idx >> 7, nl = idx & 127;
        const int n = seg * 128 + nl;
        const float v = kvf[((size_t)(b * 1024 + n)) * 1024 + 512 + h * 64 + d];
        vtbf[((size_t)bh * 64 + d) * 1024 + n] = f2bf(v);
    }
}

// ---------------------------------------------------------------------------
// Fused attention v2: MFMA QK^T -> register binary-search top-k -> softmax ->
// MFMA PV. Block = (b,h) x 16 query rows, 512 threads (8 waves).
__global__ __launch_bounds__(512, 4) void attn2(
    const unsigned short* __restrict__ qbf,
    const unsigned short* __restrict__ kbf,
    const unsigned short* __restrict__ vtbf,
    const int* __restrict__ kvals,
    const float* __restrict__ temp,
    float* __restrict__ att) {
    __shared__ float smem[16384];   // 64 KB: logits -> (P bf16 | partials)
    const int bid = blockIdx.x;
    const int swz = (bid & 7) * 512 + (bid >> 3);   // XCD-contiguous bh groups
    const int bh = swz >> 6;
    const int tile = swz & 63;
    const int b = bh >> 3, h = bh & 7;
    const int n0 = tile * 16;
    const int t = threadIdx.x;
    const int lane = t & 63, w = t >> 6;
    const int l15 = lane & 15, l4 = lane >> 4;

    const float tempv = temp[h];
    const int kval = kvals[b * 8 + h];

    // Q A-fragments straight from global (row = l15, k = l4*8+j)
    const unsigned short* qp =
        qbf + ((size_t)(b * 1024 + n0 + l15)) * 512 + h * 64 + l4 * 8;
    const bf16x8 qa0 = *reinterpret_cast<const bf16x8*>(qp);
    const bf16x8 qa1 = *reinterpret_cast<const bf16x8*>(qp + 32);

    // ---- Phase 1: QK^T (wave w -> keys [w*128, w*128+128)) ----
    const unsigned short* kbase = kbf + (size_t)bh * 1024 * 64;
#pragma unroll
    for (int f = 0; f < 8; f++) {
        const int key = w * 128 + f * 16 + l15;
        const unsigned short* kp = kbase + (size_t)key * 64 + l4 * 8;
        const bf16x8 kb0 = *reinterpret_cast<const bf16x8*>(kp);
        const bf16x8 kb1 = *reinterpret_cast<const bf16x8*>(kp + 32);
        f32x4 acc = {0.f, 0.f, 0.f, 0.f};
        acc = __builtin_amdgcn_mfma_f32_16x16x32_bf16(qa0, kb0, acc, 0, 0, 0);
        acc = __builtin_amdgcn_mfma_f32_16x16x32_bf16(qa1, kb1, acc, 0, 0, 0);
#pragma unroll
        for (int q = 0; q < 4; q++)
            smem[(l4 * 4 + q) * 1024 + key] = acc[q] * tempv;
    }
    __syncthreads();

    // ---- Phase 2: load my 2 rows into registers (monotone uint keys) ----
    const int r0 = 2 * w, r1 = r0 + 1;
    unsigned u0[16], u1[16];
#pragma unroll
    for (int i = 0; i < 16; i++) {
        u0[i] = xform_u(__float_as_uint(smem[r0 * 1024 + lane + 64 * i]));
        u1[i] = xform_u(__float_as_uint(smem[r1 * 1024 + lane + 64 * i]));
    }
    __syncthreads();     // logits LDS dead -> P may overlay

    // ---- Phase 3: exact k-th-largest via 32-step binary search (reg-only) ----
    unsigned p0 = 0, p1 = 0;
    for (int bit = 31; bit >= 0; bit--) {
        const unsigned T0 = p0 | (1u << bit), T1 = p1 | (1u << bit);
        int c0 = 0, c1 = 0;
#pragma unroll
        for (int i = 0; i < 16; i++) {
            c0 += (u0[i] >= T0) ? 1 : 0;
            c1 += (u1[i] >= T1) ? 1 : 0;
        }
#pragma unroll
        for (int off = 1; off < 64; off <<= 1) {
            c0 += __shfl_xor(c0, off, 64);
            c1 += __shfl_xor(c1, off, 64);
        }
        if (c0 >= kval) p0 = T0;
        if (c1 >= kval) p1 = T1;
    }

    // ---- Phase 3b: softmax(attn*mask) weights -> bf16 P (swizzled LDS) ----
    unsigned short* P = (unsigned short*)smem;
    {
        const unsigned* uu[2] = {u0, u1};
        const unsigned pp[2] = {p0, p1};
        const int rr[2] = {r0, r1};
#pragma unroll
        for (int rsel = 0; rsel < 2; rsel++) {
            const unsigned* u = uu[rsel];
            const unsigned p = pp[rsel];
            const int r = rr[rsel];
            float v[16];
            float mx = -3.402823466e38f;
#pragma unroll
            for (int i = 0; i < 16; i++) {
                const float a = unxform_f(u[i]);
                const float vi = (u[i] >= p) ? a : 0.f;
                v[i] = vi;
                mx = fmaxf(mx, vi);
            }
#pragma unroll
            for (int off = 1; off < 64; off <<= 1)
                mx = fmaxf(mx, __shfl_xor(mx, off, 64));
            float s = 0.f;
#pragma unroll
            for (int i = 0; i < 16; i++) s += __expf(v[i] - mx);
#pragma unroll
            for (int off = 1; off < 64; off <<= 1) s += __shfl_xor(s, off, 64);
            const float inv = 1.f / s;
#pragma unroll
            for (int i = 0; i < 16; i++) {
                const float wv = __expf(v[i] - mx) * inv;
                const int col = lane + 64 * i;
                const int kblk = col >> 3;
                P[r * 1024 + ((kblk ^ (r & 7)) << 3) + (col & 7)] = f2bf(wv);
            }
        }
    }
    __syncthreads();

    // ---- Phase 4: PV (wave w -> keys [w*128, w*128+128)) ----
    f32x4 pacc[4];
#pragma unroll
    for (int cf = 0; cf < 4; cf++) pacc[cf] = (f32x4){0.f, 0.f, 0.f, 0.f};
    const unsigned short* vtb = vtbf + (size_t)bh * 64 * 1024;
#pragma unroll
    for (int s4 = 0; s4 < 4; s4++) {
        const int kb0 = w * 128 + s4 * 32;
        const int kblk = (kb0 >> 3) + l4;
        const bf16x8 pa = *reinterpret_cast<const bf16x8*>(
            &P[l15 * 1024 + ((kblk ^ (l15 & 7)) << 3)]);
#pragma unroll
        for (int cf = 0; cf < 4; cf++) {
            const int d = cf * 16 + l15;
            const bf16x8 vb = *reinterpret_cast<const bf16x8*>(
                vtb + (size_t)d * 1024 + kb0 + l4 * 8);
            pacc[cf] = __builtin_amdgcn_mfma_f32_16x16x32_bf16(pa, vb, pacc[cf], 0, 0, 0);
        }
    }
    __syncthreads();     // all P reads done -> reuse smem for partials
    float* part = smem;  // [8][16][68]
#pragma unroll
    for (int cf = 0; cf < 4; cf++)
#pragma unroll
        for (int q = 0; q < 4; q++)
            part[w * 1088 + (l4 * 4 + q) * 68 + cf * 16 + l15] = pacc[cf][q];
    __syncthreads();
#pragma unroll
    for (int rep = 0; rep < 2; rep++) {
        const int o = t + rep * 512;
        const int row = o >> 6, d = o & 63;
        float s = 0.f;
#pragma unroll
        for (int ww = 0; ww < 8; ww++) s += part[ww * 1088 + row * 68 + d];
        att[((size_t)(b * 1024 + n0 + row)) * 512 + h * 64 + d] = s;
    }
}

// ---------------------------------------------------------------------------
__global__ __launch_bounds__(256) void transpose_out(const float* __restrict__ P,
                                                     float* __restrict__ out) {
    __shared__ float tile[32][33];
    const int blk = blockIdx.x;
    const int tcH = blk & 15;
    const int tnH = (blk >> 4) & 31;
    const int b = blk >> 9;
    const int ch0 = tcH * 32, n0 = tnH * 32;
    const int t = threadIdx.x;
    const int c = t & 31, rr = t >> 5;
#pragma unroll
    for (int it = 0; it < 4; it++) {
        const int r = rr + it * 8;
        tile[r][c] = P[((size_t)(b * 1024 + n0 + r)) * 512 + ch0 + c];
    }
    __syncthreads();
#pragma unroll
    for (int it = 0; it < 4; it++) {
        const int r = rr + it * 8;
        out[((size_t)(b * 512 + ch0 + r)) * 1024 + n0 + c] = tile[c][r];
    }
}

// ---------------------------------------------------------------------------
extern "C" void kernel_launch(void* const* d_in, const int* in_sizes, int n_in,
                              void* d_out, int out_size, void* d_ws, size_t ws_size,
                              hipStream_t stream) {
    const float* x = (const float*)d_in[0];
    const float* y = (const float*)d_in[1];
    const float* temp = (const float*)d_in[2];
    const float* q_w = (const float*)d_in[3];
    const float* kv_w = (const float*)d_in[4];
    const float* proj_w = (const float*)d_in[5];
    const float* proj_b = (const float*)d_in[6];
    const float* dk_w1 = (const float*)d_in[7];
    const float* dk_b1 = (const float*)d_in[8];
    const float* dk_w2 = (const float*)d_in[9];
    const float* dk_b2 = (const float*)d_in[10];
    const float* ln_g = (const float*)d_in[11];
    const float* ln_b = (const float*)d_in[12];
    float* out = (float*)d_out;
    float* ws = (float*)d_ws;

    float* yp = ws + 0;
    float* yn = ws + 4194304;
    float* kvf = ws + 8388608;
    unsigned short* qbf = (unsigned short*)(ws + 0);
    unsigned short* kbf = (unsigned short*)(ws + 2097152);
    unsigned short* vtbf = (unsigned short*)(ws + 4194304);
    float* att = ws + 8388608;
    float* pj = ws + 12582912;
    float* pooled = ws + 16777216;
    int* kvals = (int*)(ws + 16777216 + 4096);

    pool_kernel<<<4096, 256, 0, stream>>>(y, yp);
    ln_kernel<<<8192, 256, 0, stream>>>(yp, ln_g, ln_b, yn);
    pooled_kernel<<<4096, 256, 0, stream>>>(x, pooled);
    mlp_kernel<<<8, 128, 0, stream>>>(pooled, dk_w1, dk_b1, dk_w2, dk_b2, kvals);
    gemm64<0, 0, 0><<<dim3(16, 128), 256, 0, stream>>>(yn, kv_w, nullptr, kvf, 1024);
    reshape_kv<<<512, 256, 0, stream>>>(kvf, kbf, vtbf);
    gemm64<1, 0, 1><<<dim3(8, 128), 256, 0, stream>>>(x, q_w, nullptr, qbf, 512);
    attn2<<<4096, 512, 0, stream>>>(qbf, kbf, vtbf, kvals, temp, att);
    gemm64<0, 1, 0><<<dim3(8, 128), 256, 0, stream>>>(att, proj_w, proj_b, pj, 512);
    transpose_out<<<4096, 256, 0, stream>>>(pj, out);
}

// Round 3
// 329.665 us; speedup vs baseline: 3.3426x; 1.8403x over previous
//
#include <hip/hip_runtime.h>
#include <cstdint>
#include <cstddef>

// B=8, C=512, H=8, d=64, HW=32, N=N1=1024
// ws f32-slot layout:
//   yp    @0         (4M)   pool out; dead after ln -> reused: kbf@0 (2M), vtbf@2M (2M)
//   ynbf  @4194304   (2M slots, bf16)  ln out
//   xbf   @6291456   (2M slots, bf16)  x transposed
//   qbf   @8388608   (2M slots, bf16)  q gemm out
//   attbf @10485760  (2M slots, bf16)  attn out
//   qwbf  @12582912, kvwbf @12713984, pwbf @12976128 (bf16 weights)
//   pooled @13107200, kvals @13111296

typedef short bf16x8 __attribute__((ext_vector_type(8)));
typedef float f32x4 __attribute__((ext_vector_type(4)));

__device__ __forceinline__ unsigned short f2bf(float f) {
    unsigned u = __float_as_uint(f);
    u = (u + 0x7fffu + ((u >> 16) & 1u)) >> 16;
    return (unsigned short)u;
}
__device__ __forceinline__ unsigned xform_u(unsigned u) {
    return (u & 0x80000000u) ? ~u : (u | 0x80000000u);
}
__device__ __forceinline__ float unxform_f(unsigned k) {
    const unsigned u = (k & 0x80000000u) ? (k & 0x7fffffffu) : ~k;
    return __uint_as_float(u);
}

// ---------------------------------------------------------------------------
__global__ __launch_bounds__(256) void pool_kernel(const float* __restrict__ y,
                                                   float* __restrict__ yp) {
    __shared__ float plane[1024];
    const int bc = blockIdx.x;           // b*512 + c
    const int t = threadIdx.x;
    const float* src = y + (size_t)bc * 1024;
    *reinterpret_cast<float4*>(&plane[t * 4]) =
        reinterpret_cast<const float4*>(src)[t];
    __syncthreads();
#pragma unroll
    for (int qq = 0; qq < 4; qq++) {
        const int p = t + qq * 256;
        const int i = p >> 5, j = p & 31;
        float s3 = 0.f, s5 = 0.f, s7 = 0.f;
        float m3 = -3.402823466e38f, m5 = m3, m7 = m3;
        for (int di = -3; di <= 3; di++) {
            const int ii = i + di;
            if (ii < 0 || ii > 31) continue;
            for (int dj = -3; dj <= 3; dj++) {
                const int jj = j + dj;
                if (jj < 0 || jj > 31) continue;
                const float v = plane[(ii << 5) + jj];
                const int adi = di < 0 ? -di : di;
                const int adj = dj < 0 ? -dj : dj;
                const int rr = adi > adj ? adi : adj;
                s7 += v; m7 = fmaxf(m7, v);
                if (rr <= 2) { s5 += v; m5 = fmaxf(m5, v); }
                if (rr <= 1) { s3 += v; m3 = fmaxf(m3, v); }
            }
        }
        yp[(size_t)bc * 1024 + p] =
            s3 * (1.f / 9.f) + s5 * (1.f / 25.f) + s7 * (1.f / 49.f) + m3 + m5 + m7;
    }
}

// ---------------------------------------------------------------------------
__device__ __forceinline__ float block_sum256(float v, volatile float* scr) {
#pragma unroll
    for (int o = 32; o > 0; o >>= 1) v += __shfl_xor(v, o, 64);
    const int t = threadIdx.x;
    __syncthreads();
    if ((t & 63) == 0) scr[t >> 6] = v;
    __syncthreads();
    return scr[0] + scr[1] + scr[2] + scr[3];
}

// LayerNorm over c; output bf16 rows [b*1024+n][512]
__global__ __launch_bounds__(256) void ln_kernel(const float* __restrict__ yp,
                                                 const float* __restrict__ g,
                                                 const float* __restrict__ bt,
                                                 unsigned short* __restrict__ ynbf) {
    __shared__ float scr[4];
    const int blk = blockIdx.x;           // b*1024 + n
    const int b = blk >> 10, n = blk & 1023;
    const int t = threadIdx.x;
    const float* base = yp + (size_t)b * 512 * 1024 + n;
    const float v0 = base[(size_t)t * 1024];
    const float v1 = base[(size_t)(t + 256) * 1024];
    const float s = block_sum256(v0 + v1, scr);
    const float mu = s * (1.f / 512.f);
    const float d0 = v0 - mu, d1 = v1 - mu;
    const float s2 = block_sum256(d0 * d0 + d1 * d1, scr);
    const float rs = rsqrtf(s2 * (1.f / 512.f) + 1e-5f);
    unsigned short* o = ynbf + (size_t)blk * 512;
    o[t] = f2bf(d0 * rs * g[t] + bt[t]);
    o[t + 256] = f2bf(d1 * rs * g[t + 256] + bt[t + 256]);
}

// ---------------------------------------------------------------------------
__global__ __launch_bounds__(256) void pooled_kernel(const float* __restrict__ x,
                                                     float* __restrict__ pooled) {
    __shared__ float scr[4];
    const int bc = blockIdx.x, t = threadIdx.x;
    const float4 v = reinterpret_cast<const float4*>(x + (size_t)bc * 1024)[t];
    const float s = block_sum256(v.x + v.y + v.z + v.w, scr);
    if (t == 0) pooled[bc] = s * (1.f / 1024.f);
}

__global__ __launch_bounds__(128) void mlp_kernel(const float* __restrict__ pooled,
                                                  const float* __restrict__ w1,
                                                  const float* __restrict__ b1,
                                                  const float* __restrict__ w2,
                                                  const float* __restrict__ b2,
                                                  int* __restrict__ kvals) {
    __shared__ float pl[512];
    __shared__ float h1[128];
    __shared__ float lg[8];
    const int b = blockIdx.x, t = threadIdx.x;
#pragma unroll
    for (int i = 0; i < 4; i++) pl[t + i * 128] = pooled[b * 512 + t + i * 128];
    __syncthreads();
    float acc = b1[t];
    for (int i = 0; i < 512; i++) acc = fmaf(pl[i], w1[t * 512 + i], acc);
    h1[t] = fmaxf(acc, 0.f);
    __syncthreads();
    if (t < 8) {
        float a = b2[t];
        for (int i = 0; i < 128; i++) a = fmaf(h1[i], w2[t * 128 + i], a);
        lg[t] = a;
    }
    __syncthreads();
    if (t == 0) {
        float m = lg[0];
#pragma unroll
        for (int h = 1; h < 8; h++) m = fmaxf(m, lg[h]);
        float e[8], s = 0.f;
#pragma unroll
        for (int h = 0; h < 8; h++) { e[h] = expf(lg[h] - m); s += e[h]; }
#pragma unroll
        for (int h = 0; h < 8; h++) {
            const float p = e[h] / s;
            int kv = (int)floorf(p * 1024.f);
            kv = kv < 1 ? 1 : (kv > 1024 ? 1024 : kv);
            kvals[b * 8 + h] = kv;
        }
    }
}

// ---------------------------------------------------------------------------
// fp32 -> bf16 convert (weights)
__global__ __launch_bounds__(256) void conv_bf16(const float* __restrict__ src,
                                                 unsigned short* __restrict__ dst,
                                                 int n) {
    const int i = (blockIdx.x * 256 + threadIdx.x) * 4;
    if (i < n) {
        const float4 v = *reinterpret_cast<const float4*>(&src[i]);
        ushort4 o;
        o.x = f2bf(v.x); o.y = f2bf(v.y); o.z = f2bf(v.z); o.w = f2bf(v.w);
        *reinterpret_cast<ushort4*>(&dst[i]) = o;
    }
}

// x (b,c,n) fp32 -> xbf (b,n,c) bf16
__global__ __launch_bounds__(256) void xtrans(const float* __restrict__ x,
                                              unsigned short* __restrict__ xbf) {
    __shared__ float tile[32][36];
    const int blk = blockIdx.x;       // b(3b) | cg(4b) | ng(5b)
    const int ng = blk & 31;
    const int cg = (blk >> 5) & 15;
    const int b = blk >> 9;
    const int c0 = cg * 32, n0 = ng * 32;
    const int t = threadIdx.x;
    {
        const int cc = t >> 3, nn = (t & 7) * 4;
        const float4 v = *reinterpret_cast<const float4*>(
            &x[((size_t)(b * 512 + c0 + cc)) * 1024 + n0 + nn]);
        *reinterpret_cast<float4*>(&tile[cc][nn]) = v;
    }
    __syncthreads();
    {
        const int n = t >> 3, cb = (t & 7) * 4;
        ushort4 o;
        o.x = f2bf(tile[cb + 0][n]); o.y = f2bf(tile[cb + 1][n]);
        o.z = f2bf(tile[cb + 2][n]); o.w = f2bf(tile[cb + 3][n]);
        *reinterpret_cast<ushort4*>(
            &xbf[((size_t)(b * 1024 + n0 + n)) * 512 + c0 + cb]) = o;
    }
}

// ---------------------------------------------------------------------------
// MFMA bf16 GEMM: C[M,Nout] = A[M,512] @ W[Nout,512]^T
// EPI 0: bf16 C rows (q). EPI 1: kv -> kbf[bh][n][64] + vtbf[bh][64][n].
// EPI 2: proj -> out[b][c][n] fp32 with bias (fused transpose).
template <int EPI>
__global__ __launch_bounds__(256, 4) void gemm_mfma(
    const unsigned short* __restrict__ A,
    const unsigned short* __restrict__ W,
    const float* __restrict__ bias,
    void* __restrict__ out0,
    unsigned short* __restrict__ out1,
    int Nout) {
    __shared__ unsigned short As[128][72];
    __shared__ unsigned short Ws[128][72];
    const int t = threadIdx.x;
    const int w = t >> 6, lane = t & 63;
    const int l15 = lane & 15, l4 = lane >> 4;
    const int n0 = blockIdx.x * 128;
    const int m0 = blockIdx.y * 128;
    const int wm = (w >> 1) * 64, wn = (w & 1) * 64;
    f32x4 acc[4][4];
#pragma unroll
    for (int i = 0; i < 4; i++)
#pragma unroll
        for (int j = 0; j < 4; j++) acc[i][j] = (f32x4){0.f, 0.f, 0.f, 0.f};
    const int srow = t >> 3, sp = t & 7;
    const unsigned short* aSrc = A + (size_t)(m0 + srow) * 512 + sp * 8;
    const unsigned short* wSrc = W + (size_t)(n0 + srow) * 512 + sp * 8;
#pragma unroll 1
    for (int k0 = 0; k0 < 512; k0 += 64) {
        __syncthreads();
#pragma unroll
        for (int i = 0; i < 4; i++) {
            const int row = srow + i * 32;
            *reinterpret_cast<bf16x8*>(&As[row][sp * 8]) =
                *reinterpret_cast<const bf16x8*>(aSrc + (size_t)i * 32 * 512 + k0);
            *reinterpret_cast<bf16x8*>(&Ws[row][sp * 8]) =
                *reinterpret_cast<const bf16x8*>(wSrc + (size_t)i * 32 * 512 + k0);
        }
        __syncthreads();
#pragma unroll
        for (int kk = 0; kk < 2; kk++) {
            bf16x8 af[4], wf[4];
#pragma unroll
            for (int f = 0; f < 4; f++) {
                af[f] = *reinterpret_cast<const bf16x8*>(
                    &As[wm + f * 16 + l15][kk * 32 + l4 * 8]);
                wf[f] = *reinterpret_cast<const bf16x8*>(
                    &Ws[wn + f * 16 + l15][kk * 32 + l4 * 8]);
            }
#pragma unroll
            for (int fm = 0; fm < 4; fm++)
#pragma unroll
                for (int fn = 0; fn < 4; fn++)
                    acc[fm][fn] = __builtin_amdgcn_mfma_f32_16x16x32_bf16(
                        af[fm], wf[fn], acc[fm][fn], 0, 0, 0);
        }
    }
    if (EPI == 0) {
        unsigned short* C = (unsigned short*)out0;
#pragma unroll
        for (int fm = 0; fm < 4; fm++) {
            const int row = m0 + wm + fm * 16 + l4 * 4;
#pragma unroll
            for (int fn = 0; fn < 4; fn++) {
                const int col = n0 + wn + fn * 16 + l15;
#pragma unroll
                for (int q = 0; q < 4; q++)
                    C[(size_t)(row + q) * Nout + col] = f2bf(acc[fm][fn][q]);
            }
        }
    } else if (EPI == 1) {
        unsigned short* kb = (unsigned short*)out0;
        const int b = m0 >> 10;
        const int cw = n0 + wn;
        const bool isv = cw >= 512;
        const int hh = (cw & 511) >> 6;
        const size_t bh = (size_t)(b * 8 + hh);
#pragma unroll
        for (int fm = 0; fm < 4; fm++) {
            const int n = (m0 + wm + fm * 16 + l4 * 4) & 1023;
#pragma unroll
            for (int fn = 0; fn < 4; fn++) {
                const int d = fn * 16 + l15;
                if (!isv) {
#pragma unroll
                    for (int q = 0; q < 4; q++)
                        kb[(bh * 1024 + n + q) * 64 + d] = f2bf(acc[fm][fn][q]);
                } else {
                    ushort4 v4;
                    v4.x = f2bf(acc[fm][fn][0]); v4.y = f2bf(acc[fm][fn][1]);
                    v4.z = f2bf(acc[fm][fn][2]); v4.w = f2bf(acc[fm][fn][3]);
                    *reinterpret_cast<ushort4*>(&out1[(bh * 64 + d) * 1024 + n]) = v4;
                }
            }
        }
    } else {
        float* outp = (float*)out0;
        const int b = m0 >> 10;
#pragma unroll
        for (int fm = 0; fm < 4; fm++) {
            const int n = (m0 + wm + fm * 16 + l4 * 4) & 1023;
#pragma unroll
            for (int fn = 0; fn < 4; fn++) {
                const int c = n0 + wn + fn * 16 + l15;
                const float bv = bias[c];
                float4 o;
                o.x = acc[fm][fn][0] + bv; o.y = acc[fm][fn][1] + bv;
                o.z = acc[fm][fn][2] + bv; o.w = acc[fm][fn][3] + bv;
                *reinterpret_cast<float4*>(
                    &outp[((size_t)(b * 512) + c) * 1024 + n]) = o;
            }
        }
    }
}

// ---------------------------------------------------------------------------
// Fused attention v3: MFMA QK^T -> ballot-count binary-search top-k (early
// exit) -> softmax -> MFMA PV -> bf16 out. Block = (b,h) x 16 rows, 8 waves.
__global__ __launch_bounds__(512, 4) void attn3(
    const unsigned short* __restrict__ qbf,
    const unsigned short* __restrict__ kbf,
    const unsigned short* __restrict__ vtbf,
    const int* __restrict__ kvals,
    const float* __restrict__ temp,
    unsigned short* __restrict__ attbf) {
    __shared__ float smem[16384];   // 64 KB: logits -> (P bf16 | partials)
    const int bid = blockIdx.x;
    const int swz = (bid & 7) * 512 + (bid >> 3);   // XCD-contiguous bh groups
    const int bh = swz >> 6;
    const int tile = swz & 63;
    const int b = bh >> 3, h = bh & 7;
    const int n0 = tile * 16;
    const int t = threadIdx.x;
    const int lane = t & 63, w = t >> 6;
    const int l15 = lane & 15, l4 = lane >> 4;

    const float tempv = temp[h];
    const int kval = kvals[b * 8 + h];

    const unsigned short* qp =
        qbf + ((size_t)(b * 1024 + n0 + l15)) * 512 + h * 64 + l4 * 8;
    const bf16x8 qa0 = *reinterpret_cast<const bf16x8*>(qp);
    const bf16x8 qa1 = *reinterpret_cast<const bf16x8*>(qp + 32);

    // ---- Phase 1: QK^T ----
    const unsigned short* kbase = kbf + (size_t)bh * 65536;
#pragma unroll
    for (int f = 0; f < 8; f++) {
        const int key = w * 128 + f * 16 + l15;
        const unsigned short* kp = kbase + (size_t)key * 64 + l4 * 8;
        const bf16x8 kb0 = *reinterpret_cast<const bf16x8*>(kp);
        const bf16x8 kb1 = *reinterpret_cast<const bf16x8*>(kp + 32);
        f32x4 acc = {0.f, 0.f, 0.f, 0.f};
        acc = __builtin_amdgcn_mfma_f32_16x16x32_bf16(qa0, kb0, acc, 0, 0, 0);
        acc = __builtin_amdgcn_mfma_f32_16x16x32_bf16(qa1, kb1, acc, 0, 0, 0);
#pragma unroll
        for (int q = 0; q < 4; q++)
            smem[(l4 * 4 + q) * 1024 + key] = acc[q] * tempv;
    }
    __syncthreads();

    // ---- Phase 2: my 2 rows into registers (vector loads; monotone keys) ----
    const int r0 = 2 * w, r1 = r0 + 1;
    unsigned u0[16], u1[16];
#pragma unroll
    for (int i = 0; i < 4; i++) {
        const float4 f0 = *reinterpret_cast<const float4*>(
            &smem[r0 * 1024 + i * 256 + lane * 4]);
        const float4 f1 = *reinterpret_cast<const float4*>(
            &smem[r1 * 1024 + i * 256 + lane * 4]);
        u0[4 * i + 0] = xform_u(__float_as_uint(f0.x));
        u0[4 * i + 1] = xform_u(__float_as_uint(f0.y));
        u0[4 * i + 2] = xform_u(__float_as_uint(f0.z));
        u0[4 * i + 3] = xform_u(__float_as_uint(f0.w));
        u1[4 * i + 0] = xform_u(__float_as_uint(f1.x));
        u1[4 * i + 1] = xform_u(__float_as_uint(f1.y));
        u1[4 * i + 2] = xform_u(__float_as_uint(f1.z));
        u1[4 * i + 3] = xform_u(__float_as_uint(f1.w));
    }
    __syncthreads();     // logits LDS dead -> P overlays

    // ---- Phase 3: k-th largest via ballot-count binary search, early exit ----
    unsigned p0 = 0, p1 = 0;
    int done = 0;
    for (int bit = 31; bit >= 0; bit--) {
        if (!(done & 1)) {
            const unsigned T = p0 | (1u << bit);
            int c = 0;
#pragma unroll
            for (int i = 0; i < 16; i++)
                c += (int)__popcll(__ballot(u0[i] >= T));
            if (c >= kval) { p0 = T; if (c == kval) done |= 1; }
        }
        if (!(done & 2)) {
            const unsigned T = p1 | (1u << bit);
            int c = 0;
#pragma unroll
            for (int i = 0; i < 16; i++)
                c += (int)__popcll(__ballot(u1[i] >= T));
            if (c >= kval) { p1 = T; if (c == kval) done |= 2; }
        }
        if (done == 3) break;
    }

    // ---- Phase 3b: softmax(attn*mask) -> bf16 P (swizzled LDS) ----
    unsigned short* P = (unsigned short*)smem;
    {
        const unsigned pp[2] = {p0, p1};
        const int rr2[2] = {r0, r1};
#pragma unroll
        for (int rsel = 0; rsel < 2; rsel++) {
            const unsigned* u = rsel ? u1 : u0;
            const unsigned p = pp[rsel];
            const int r = rr2[rsel];
            float v[16];
            float mx = -3.402823466e38f;
#pragma unroll
            for (int i = 0; i < 16; i++) {
                const float a = unxform_f(u[i]);
                const float vi = (u[i] >= p) ? a : 0.f;
                v[i] = vi;
                mx = fmaxf(mx, vi);
            }
#pragma unroll
            for (int off = 1; off < 64; off <<= 1)
                mx = fmaxf(mx, __shfl_xor(mx, off, 64));
            float s = 0.f;
#pragma unroll
            for (int i = 0; i < 16; i++) {
                const float ei = __expf(v[i] - mx);
                v[i] = ei;
                s += ei;
            }
#pragma unroll
            for (int off = 1; off < 64; off <<= 1) s += __shfl_xor(s, off, 64);
            const float inv = 1.f / s;
#pragma unroll
            for (int g = 0; g < 4; g++) {
                ushort4 pk;
                pk.x = f2bf(v[g * 4 + 0] * inv);
                pk.y = f2bf(v[g * 4 + 1] * inv);
                pk.z = f2bf(v[g * 4 + 2] * inv);
                pk.w = f2bf(v[g * 4 + 3] * inv);
                *reinterpret_cast<ushort4*>(
                    &P[r * 1024 + ((((lane >> 1) + 32 * g) ^ (r & 7)) << 3) +
                       (lane & 1) * 4]) = pk;
            }
        }
    }
    __syncthreads();

    // ---- Phase 4: PV ----
    f32x4 pacc[4];
#pragma unroll
    for (int cf = 0; cf < 4; cf++) pacc[cf] = (f32x4){0.f, 0.f, 0.f, 0.f};
    const unsigned short* vtb = vtbf + (size_t)bh * 65536;
#pragma unroll
    for (int s4 = 0; s4 < 4; s4++) {
        const int kb0 = w * 128 + s4 * 32;
        const int kblk = (kb0 >> 3) + l4;
        const bf16x8 pa = *reinterpret_cast<const bf16x8*>(
            &P[l15 * 1024 + ((kblk ^ (l15 & 7)) << 3)]);
#pragma unroll
        for (int cf = 0; cf < 4; cf++) {
            const int d = cf * 16 + l15;
            const bf16x8 vb = *reinterpret_cast<const bf16x8*>(
                vtb + (size_t)d * 1024 + kb0 + l4 * 8);
            pacc[cf] =
                __builtin_amdgcn_mfma_f32_16x16x32_bf16(pa, vb, pacc[cf], 0, 0, 0);
        }
    }
    __syncthreads();     // P reads done -> reuse smem for partials
    float* part = smem;  // [8][16][68]
#pragma unroll
    for (int cf = 0; cf < 4; cf++)
#pragma unroll
        for (int q = 0; q < 4; q++)
            part[w * 1088 + (l4 * 4 + q) * 68 + cf * 16 + l15] = pacc[cf][q];
    __syncthreads();
#pragma unroll
    for (int rep = 0; rep < 2; rep++) {
        const int o = t + rep * 512;
        const int row = o >> 6, d = o & 63;
        float s = 0.f;
#pragma unroll
        for (int ww = 0; ww < 8; ww++) s += part[ww * 1088 + row * 68 + d];
        attbf[((size_t)(b * 1024 + n0 + row)) * 512 + h * 64 + d] = f2bf(s);
    }
}

// ---------------------------------------------------------------------------
extern "C" void kernel_launch(void* const* d_in, const int* in_sizes, int n_in,
                              void* d_out, int out_size, void* d_ws, size_t ws_size,
                              hipStream_t stream) {
    const float* x = (const float*)d_in[0];
    const float* y = (const float*)d_in[1];
    const float* temp = (const float*)d_in[2];
    const float* q_w = (const float*)d_in[3];
    const float* kv_w = (const float*)d_in[4];
    const float* proj_w = (const float*)d_in[5];
    const float* proj_b = (const float*)d_in[6];
    const float* dk_w1 = (const float*)d_in[7];
    const float* dk_b1 = (const float*)d_in[8];
    const float* dk_w2 = (const float*)d_in[9];
    const float* dk_b2 = (const float*)d_in[10];
    const float* ln_g = (const float*)d_in[11];
    const float* ln_b = (const float*)d_in[12];
    float* out = (float*)d_out;
    float* ws = (float*)d_ws;

    float* yp = ws;
    unsigned short* ynbf = (unsigned short*)(ws + 4194304);
    unsigned short* xbf = (unsigned short*)(ws + 6291456);
    unsigned short* qbf = (unsigned short*)(ws + 8388608);
    unsigned short* attbf = (unsigned short*)(ws + 10485760);
    unsigned short* qwbf = (unsigned short*)(ws + 12582912);
    unsigned short* kvwbf = (unsigned short*)(ws + 12713984);
    unsigned short* pwbf = (unsigned short*)(ws + 12976128);
    float* pooled = ws + 13107200;
    int* kvals = (int*)(ws + 13111296);
    unsigned short* kbf = (unsigned short*)ws;               // reuse yp after ln
    unsigned short* vtbf = (unsigned short*)(ws + 2097152);  // reuse yp after ln

    pool_kernel<<<4096, 256, 0, stream>>>(y, yp);
    xtrans<<<4096, 256, 0, stream>>>(x, xbf);
    pooled_kernel<<<4096, 256, 0, stream>>>(x, pooled);
    mlp_kernel<<<8, 128, 0, stream>>>(pooled, dk_w1, dk_b1, dk_w2, dk_b2, kvals);
    conv_bf16<<<256, 256, 0, stream>>>(q_w, qwbf, 262144);
    conv_bf16<<<512, 256, 0, stream>>>(kv_w, kvwbf, 524288);
    conv_bf16<<<256, 256, 0, stream>>>(proj_w, pwbf, 262144);
    ln_kernel<<<8192, 256, 0, stream>>>(yp, ln_g, ln_b, ynbf);
    gemm_mfma<1><<<dim3(8, 64), 256, 0, stream>>>(ynbf, kvwbf, nullptr, kbf, vtbf, 1024);
    gemm_mfma<0><<<dim3(4, 64), 256, 0, stream>>>(xbf, qwbf, nullptr, qbf, nullptr, 512);
    attn3<<<4096, 512, 0, stream>>>(qbf, kbf, vtbf, kvals, temp, attbf);
    gemm_mfma<2><<<dim3(4, 64), 256, 0, stream>>>(attbf, pwbf, proj_b, out, nullptr, 512);
}

// Round 4
// 293.712 us; speedup vs baseline: 3.7518x; 1.1224x over previous
//
#include <hip/hip_runtime.h>
#include <cstdint>
#include <cstddef>

// B=8, C=512, H=8, d=64, HW=32, N=N1=1024
// ws f32-slot layout:
//   yp    @0         (4M)   pool out; dead after ln -> reused: kbf@0 (2M), vtbf@2M (2M)
//   ynbf  @4194304   (2M slots, bf16)  ln out
//   xbf   @6291456   (2M slots, bf16)  x transposed
//   qbf   @8388608   (2M slots, bf16)  q gemm out
//   attbf @10485760  (2M slots, bf16)  attn out
//   qwbf  @12582912, kvwbf @12713984, pwbf @12976128 (bf16 weights)
//   pooled @13107200, kvals @13111296

typedef short bf16x8 __attribute__((ext_vector_type(8)));
typedef float f32x4 __attribute__((ext_vector_type(4)));

__device__ __forceinline__ unsigned short f2bf(float f) {
    unsigned u = __float_as_uint(f);
    u = (u + 0x7fffu + ((u >> 16) & 1u)) >> 16;
    return (unsigned short)u;
}
__device__ __forceinline__ unsigned xform_u(unsigned u) {
    return (u & 0x80000000u) ? ~u : (u | 0x80000000u);
}
__device__ __forceinline__ float unxform_f(unsigned k) {
    const unsigned u = (k & 0x80000000u) ? (k & 0x7fffffffu) : ~k;
    return __uint_as_float(u);
}

// ---------------------------------------------------------------------------
// Separable multi-scale pooling. One block = one (b,c) plane.
// Horizontal pass (38 padded rows x 32 cols) -> vertical pass (32x32).
__global__ __launch_bounds__(256) void pool_kernel(const float* __restrict__ y,
                                                   float* __restrict__ yp) {
    __shared__ float pz[1520];   // [38][40] zero-padded
    __shared__ float pm[1520];   // [38][40] -max-padded
    __shared__ float hz3[1216], hz5[1216], hz7[1216];
    __shared__ float hm3[1216], hm5[1216], hm7[1216];
    const int bc = blockIdx.x;
    const int t = threadIdx.x;
    for (int i = t; i < 1520; i += 256) { pz[i] = 0.f; pm[i] = -3.402823466e38f; }
    __syncthreads();
    const float4 v = reinterpret_cast<const float4*>(y + (size_t)bc * 1024)[t];
    {
        const int r = t >> 3, c = (t & 7) * 4;
        float* dz = &pz[(r + 3) * 40 + c + 3];
        float* dm = &pm[(r + 3) * 40 + c + 3];
        dz[0] = v.x; dz[1] = v.y; dz[2] = v.z; dz[3] = v.w;
        dm[0] = v.x; dm[1] = v.y; dm[2] = v.z; dm[3] = v.w;
    }
    __syncthreads();
    // horizontal: 38 x 32
    for (int hp = t; hp < 1216; hp += 256) {
        const int i = hp >> 5, j = hp & 31;
        const float* rz = &pz[i * 40 + j + 3];
        const float* rm = &pm[i * 40 + j + 3];
        const float s3 = rz[-1] + rz[0] + rz[1];
        const float s5 = s3 + rz[-2] + rz[2];
        const float s7 = s5 + rz[-3] + rz[3];
        const float m3 = fmaxf(fmaxf(rm[-1], rm[0]), rm[1]);
        const float m5 = fmaxf(m3, fmaxf(rm[-2], rm[2]));
        const float m7 = fmaxf(m5, fmaxf(rm[-3], rm[3]));
        hz3[hp] = s3; hz5[hp] = s5; hz7[hp] = s7;
        hm3[hp] = m3; hm5[hp] = m5; hm7[hp] = m7;
    }
    __syncthreads();
    // vertical: 32 x 32
    float* dst = yp + (size_t)bc * 1024;
#pragma unroll
    for (int q = 0; q < 4; q++) {
        const int p = q * 256 + t;
        const int i = p >> 5, j = p & 31;
        const int ic = (i + 3) * 32 + j;
        const float s3 = hz3[ic - 32] + hz3[ic] + hz3[ic + 32];
        const float s5 = hz5[ic - 64] + hz5[ic - 32] + hz5[ic] + hz5[ic + 32] +
                         hz5[ic + 64];
        const float s7 = hz7[ic - 96] + hz7[ic - 64] + hz7[ic - 32] + hz7[ic] +
                         hz7[ic + 32] + hz7[ic + 64] + hz7[ic + 96];
        const float m3 = fmaxf(fmaxf(hm3[ic - 32], hm3[ic]), hm3[ic + 32]);
        const float m5 = fmaxf(fmaxf(fmaxf(hm5[ic - 64], hm5[ic - 32]),
                                     fmaxf(hm5[ic], hm5[ic + 32])), hm5[ic + 64]);
        float m7 = fmaxf(fmaxf(hm7[ic - 96], hm7[ic - 64]),
                         fmaxf(hm7[ic - 32], hm7[ic]));
        m7 = fmaxf(m7, fmaxf(fmaxf(hm7[ic + 32], hm7[ic + 64]), hm7[ic + 96]));
        dst[p] = s3 * (1.f / 9.f) + s5 * (1.f / 25.f) + s7 * (1.f / 49.f) +
                 m3 + m5 + m7;
    }
}

// ---------------------------------------------------------------------------
__device__ __forceinline__ float block_sum256(float v, volatile float* scr) {
#pragma unroll
    for (int o = 32; o > 0; o >>= 1) v += __shfl_xor(v, o, 64);
    const int t = threadIdx.x;
    __syncthreads();
    if ((t & 63) == 0) scr[t >> 6] = v;
    __syncthreads();
    return scr[0] + scr[1] + scr[2] + scr[3];
}

// LayerNorm over c; output bf16 rows [b*1024+n][512]
__global__ __launch_bounds__(256) void ln_kernel(const float* __restrict__ yp,
                                                 const float* __restrict__ g,
                                                 const float* __restrict__ bt,
                                                 unsigned short* __restrict__ ynbf) {
    __shared__ float scr[4];
    const int blk = blockIdx.x;           // b*1024 + n
    const int b = blk >> 10, n = blk & 1023;
    const int t = threadIdx.x;
    const float* base = yp + (size_t)b * 512 * 1024 + n;
    const float v0 = base[(size_t)t * 1024];
    const float v1 = base[(size_t)(t + 256) * 1024];
    const float s = block_sum256(v0 + v1, scr);
    const float mu = s * (1.f / 512.f);
    const float d0 = v0 - mu, d1 = v1 - mu;
    const float s2 = block_sum256(d0 * d0 + d1 * d1, scr);
    const float rs = rsqrtf(s2 * (1.f / 512.f) + 1e-5f);
    unsigned short* o = ynbf + (size_t)blk * 512;
    o[t] = f2bf(d0 * rs * g[t] + bt[t]);
    o[t + 256] = f2bf(d1 * rs * g[t + 256] + bt[t + 256]);
}

// ---------------------------------------------------------------------------
__global__ __launch_bounds__(256) void pooled_kernel(const float* __restrict__ x,
                                                     float* __restrict__ pooled) {
    __shared__ float scr[4];
    const int bc = blockIdx.x, t = threadIdx.x;
    const float4 v = reinterpret_cast<const float4*>(x + (size_t)bc * 1024)[t];
    const float s = block_sum256(v.x + v.y + v.z + v.w, scr);
    if (t == 0) pooled[bc] = s * (1.f / 1024.f);
}

__global__ __launch_bounds__(128) void mlp_kernel(const float* __restrict__ pooled,
                                                  const float* __restrict__ w1,
                                                  const float* __restrict__ b1,
                                                  const float* __restrict__ w2,
                                                  const float* __restrict__ b2,
                                                  int* __restrict__ kvals) {
    __shared__ float pl[512];
    __shared__ float h1[128];
    __shared__ float lg[8];
    const int b = blockIdx.x, t = threadIdx.x;
#pragma unroll
    for (int i = 0; i < 4; i++) pl[t + i * 128] = pooled[b * 512 + t + i * 128];
    __syncthreads();
    float acc = b1[t];
    for (int i = 0; i < 512; i++) acc = fmaf(pl[i], w1[t * 512 + i], acc);
    h1[t] = fmaxf(acc, 0.f);
    __syncthreads();
    if (t < 8) {
        float a = b2[t];
        for (int i = 0; i < 128; i++) a = fmaf(h1[i], w2[t * 128 + i], a);
        lg[t] = a;
    }
    __syncthreads();
    if (t == 0) {
        float m = lg[0];
#pragma unroll
        for (int h = 1; h < 8; h++) m = fmaxf(m, lg[h]);
        float e[8], s = 0.f;
#pragma unroll
        for (int h = 0; h < 8; h++) { e[h] = expf(lg[h] - m); s += e[h]; }
#pragma unroll
        for (int h = 0; h < 8; h++) {
            const float p = e[h] / s;
            int kv = (int)floorf(p * 1024.f);
            kv = kv < 1 ? 1 : (kv > 1024 ? 1024 : kv);
            kvals[b * 8 + h] = kv;
        }
    }
}

// ---------------------------------------------------------------------------
// All three weight matrices -> bf16 in one launch (1M elements total).
__global__ __launch_bounds__(256) void convw(const float* __restrict__ qw,
                                             const float* __restrict__ kvw,
                                             const float* __restrict__ pw,
                                             unsigned short* __restrict__ dq,
                                             unsigned short* __restrict__ dkv,
                                             unsigned short* __restrict__ dp) {
    const int gid = blockIdx.x * 256 + threadIdx.x;
    const float* s; unsigned short* d; int off;
    if (gid < 65536) { s = qw; d = dq; off = gid * 4; }
    else if (gid < 196608) { s = kvw; d = dkv; off = gid * 4 - 262144; }
    else { s = pw; d = dp; off = gid * 4 - 786432; }
    const float4 v = *reinterpret_cast<const float4*>(&s[off]);
    ushort4 o;
    o.x = f2bf(v.x); o.y = f2bf(v.y); o.z = f2bf(v.z); o.w = f2bf(v.w);
    *reinterpret_cast<ushort4*>(&d[off]) = o;
}

// x (b,c,n) fp32 -> xbf (b,n,c) bf16
__global__ __launch_bounds__(256) void xtrans(const float* __restrict__ x,
                                              unsigned short* __restrict__ xbf) {
    __shared__ float tile[32][36];
    const int blk = blockIdx.x;       // b(3b) | cg(4b) | ng(5b)
    const int ng = blk & 31;
    const int cg = (blk >> 5) & 15;
    const int b = blk >> 9;
    const int c0 = cg * 32, n0 = ng * 32;
    const int t = threadIdx.x;
    {
        const int cc = t >> 3, nn = (t & 7) * 4;
        const float4 v = *reinterpret_cast<const float4*>(
            &x[((size_t)(b * 512 + c0 + cc)) * 1024 + n0 + nn]);
        *reinterpret_cast<float4*>(&tile[cc][nn]) = v;
    }
    __syncthreads();
    {
        const int n = t >> 3, cb = (t & 7) * 4;
        ushort4 o;
        o.x = f2bf(tile[cb + 0][n]); o.y = f2bf(tile[cb + 1][n]);
        o.z = f2bf(tile[cb + 2][n]); o.w = f2bf(tile[cb + 3][n]);
        *reinterpret_cast<ushort4*>(
            &xbf[((size_t)(b * 1024 + n0 + n)) * 512 + c0 + cb]) = o;
    }
}

// ---------------------------------------------------------------------------
// MFMA bf16 GEMM: C[M,Nout] = A[M,512] @ W[Nout,512]^T
// EPI 0: bf16 C rows (q). EPI 1: kv -> kbf[bh][n][64] + vtbf[bh][64][n].
// EPI 2: proj -> out[b][c][n] fp32 with bias (fused transpose).
template <int EPI>
__global__ __launch_bounds__(256, 4) void gemm_mfma(
    const unsigned short* __restrict__ A,
    const unsigned short* __restrict__ W,
    const float* __restrict__ bias,
    void* __restrict__ out0,
    unsigned short* __restrict__ out1,
    int Nout) {
    __shared__ unsigned short As[128][72];
    __shared__ unsigned short Ws[128][72];
    const int t = threadIdx.x;
    const int w = t >> 6, lane = t & 63;
    const int l15 = lane & 15, l4 = lane >> 4;
    const int n0 = blockIdx.x * 128;
    const int m0 = blockIdx.y * 128;
    const int wm = (w >> 1) * 64, wn = (w & 1) * 64;
    f32x4 acc[4][4];
#pragma unroll
    for (int i = 0; i < 4; i++)
#pragma unroll
        for (int j = 0; j < 4; j++) acc[i][j] = (f32x4){0.f, 0.f, 0.f, 0.f};
    const int srow = t >> 3, sp = t & 7;
    const unsigned short* aSrc = A + (size_t)(m0 + srow) * 512 + sp * 8;
    const unsigned short* wSrc = W + (size_t)(n0 + srow) * 512 + sp * 8;
#pragma unroll 1
    for (int k0 = 0; k0 < 512; k0 += 64) {
        __syncthreads();
#pragma unroll
        for (int i = 0; i < 4; i++) {
            const int row = srow + i * 32;
            *reinterpret_cast<bf16x8*>(&As[row][sp * 8]) =
                *reinterpret_cast<const bf16x8*>(aSrc + (size_t)i * 32 * 512 + k0);
            *reinterpret_cast<bf16x8*>(&Ws[row][sp * 8]) =
                *reinterpret_cast<const bf16x8*>(wSrc + (size_t)i * 32 * 512 + k0);
        }
        __syncthreads();
#pragma unroll
        for (int kk = 0; kk < 2; kk++) {
            bf16x8 af[4], wf[4];
#pragma unroll
            for (int f = 0; f < 4; f++) {
                af[f] = *reinterpret_cast<const bf16x8*>(
                    &As[wm + f * 16 + l15][kk * 32 + l4 * 8]);
                wf[f] = *reinterpret_cast<const bf16x8*>(
                    &Ws[wn + f * 16 + l15][kk * 32 + l4 * 8]);
            }
#pragma unroll
            for (int fm = 0; fm < 4; fm++)
#pragma unroll
                for (int fn = 0; fn < 4; fn++)
                    acc[fm][fn] = __builtin_amdgcn_mfma_f32_16x16x32_bf16(
                        af[fm], wf[fn], acc[fm][fn], 0, 0, 0);
        }
    }
    if (EPI == 0) {
        unsigned short* C = (unsigned short*)out0;
#pragma unroll
        for (int fm = 0; fm < 4; fm++) {
            const int row = m0 + wm + fm * 16 + l4 * 4;
#pragma unroll
            for (int fn = 0; fn < 4; fn++) {
                const int col = n0 + wn + fn * 16 + l15;
#pragma unroll
                for (int q = 0; q < 4; q++)
                    C[(size_t)(row + q) * Nout + col] = f2bf(acc[fm][fn][q]);
            }
        }
    } else if (EPI == 1) {
        unsigned short* kb = (unsigned short*)out0;
        const int b = m0 >> 10;
        const int cw = n0 + wn;
        const bool isv = cw >= 512;
        const int hh = (cw & 511) >> 6;
        const size_t bh = (size_t)(b * 8 + hh);
#pragma unroll
        for (int fm = 0; fm < 4; fm++) {
            const int n = (m0 + wm + fm * 16 + l4 * 4) & 1023;
#pragma unroll
            for (int fn = 0; fn < 4; fn++) {
                const int d = fn * 16 + l15;
                if (!isv) {
#pragma unroll
                    for (int q = 0; q < 4; q++)
                        kb[(bh * 1024 + n + q) * 64 + d] = f2bf(acc[fm][fn][q]);
                } else {
                    ushort4 v4;
                    v4.x = f2bf(acc[fm][fn][0]); v4.y = f2bf(acc[fm][fn][1]);
                    v4.z = f2bf(acc[fm][fn][2]); v4.w = f2bf(acc[fm][fn][3]);
                    *reinterpret_cast<ushort4*>(&out1[(bh * 64 + d) * 1024 + n]) = v4;
                }
            }
        }
    } else {
        float* outp = (float*)out0;
        const int b = m0 >> 10;
#pragma unroll
        for (int fm = 0; fm < 4; fm++) {
            const int n = (m0 + wm + fm * 16 + l4 * 4) & 1023;
#pragma unroll
            for (int fn = 0; fn < 4; fn++) {
                const int c = n0 + wn + fn * 16 + l15;
                const float bv = bias[c];
                float4 o;
                o.x = acc[fm][fn][0] + bv; o.y = acc[fm][fn][1] + bv;
                o.z = acc[fm][fn][2] + bv; o.w = acc[fm][fn][3] + bv;
                *reinterpret_cast<float4*>(
                    &outp[((size_t)(b * 512) + c) * 1024 + n]) = o;
            }
        }
    }
}

// ---------------------------------------------------------------------------
// Fused attention v4: 16 waves, 1 query row per wave. MFMA QK^T ->
// ballot binary-search top-k -> softmax -> MFMA PV ((kseg,cf) split).
__global__ __launch_bounds__(1024, 8) void attn4(
    const unsigned short* __restrict__ qbf,
    const unsigned short* __restrict__ kbf,
    const unsigned short* __restrict__ vtbf,
    const int* __restrict__ kvals,
    const float* __restrict__ temp,
    unsigned short* __restrict__ attbf) {
    __shared__ float smem[16384];   // 64 KB: logits -> (P bf16 | partials)
    const int bid = blockIdx.x;
    const int swz = (bid & 7) * 512 + (bid >> 3);   // XCD-contiguous bh groups
    const int bh = swz >> 6;
    const int tile = swz & 63;
    const int b = bh >> 3, h = bh & 7;
    const int n0 = tile * 16;
    const int t = threadIdx.x;
    const int lane = t & 63, w = t >> 6;   // w = 0..15 (also: my query row)
    const int l15 = lane & 15, l4 = lane >> 4;

    const float tempv = temp[h];
    const int kval = kvals[b * 8 + h];

    const unsigned short* qp =
        qbf + ((size_t)(b * 1024 + n0 + l15)) * 512 + h * 64 + l4 * 8;
    const bf16x8 qa0 = *reinterpret_cast<const bf16x8*>(qp);
    const bf16x8 qa1 = *reinterpret_cast<const bf16x8*>(qp + 32);

    // ---- Phase 1: QK^T; wave w -> keys [w*64, w*64+64) ----
    const unsigned short* kbase = kbf + (size_t)bh * 65536;
#pragma unroll
    for (int f = 0; f < 4; f++) {
        const int key = w * 64 + f * 16 + l15;
        const unsigned short* kp = kbase + (size_t)key * 64 + l4 * 8;
        const bf16x8 kb0 = *reinterpret_cast<const bf16x8*>(kp);
        const bf16x8 kb1 = *reinterpret_cast<const bf16x8*>(kp + 32);
        f32x4 acc = {0.f, 0.f, 0.f, 0.f};
        acc = __builtin_amdgcn_mfma_f32_16x16x32_bf16(qa0, kb0, acc, 0, 0, 0);
        acc = __builtin_amdgcn_mfma_f32_16x16x32_bf16(qa1, kb1, acc, 0, 0, 0);
#pragma unroll
        for (int q = 0; q < 4; q++)
            smem[(l4 * 4 + q) * 1024 + key] = acc[q] * tempv;
    }
    __syncthreads();

    // ---- Phase 2: my row into registers (monotone uint keys) ----
    unsigned u[16];
#pragma unroll
    for (int i = 0; i < 4; i++) {
        const float4 f0 = *reinterpret_cast<const float4*>(
            &smem[w * 1024 + i * 256 + lane * 4]);
        u[4 * i + 0] = xform_u(__float_as_uint(f0.x));
        u[4 * i + 1] = xform_u(__float_as_uint(f0.y));
        u[4 * i + 2] = xform_u(__float_as_uint(f0.z));
        u[4 * i + 3] = xform_u(__float_as_uint(f0.w));
    }
    __syncthreads();     // logits LDS dead -> P overlays

    // ---- Phase 3: k-th largest via ballot-count binary search, early exit ----
    unsigned p = 0;
    for (int bit = 31; bit >= 0; bit--) {
        const unsigned T = p | (1u << bit);
        int c = 0;
#pragma unroll
        for (int i = 0; i < 16; i++)
            c += (int)__popcll(__ballot(u[i] >= T));
        if (c >= kval) {
            p = T;
            if (c == kval) break;
        }
    }

    // ---- Phase 3b: softmax(attn*mask) -> bf16 P (swizzled LDS) ----
    unsigned short* P = (unsigned short*)smem;
    {
        float v[16];
        float mx = -3.402823466e38f;
#pragma unroll
        for (int i = 0; i < 16; i++) {
            const float a = unxform_f(u[i]);
            const float vi = (u[i] >= p) ? a : 0.f;
            v[i] = vi;
            mx = fmaxf(mx, vi);
        }
#pragma unroll
        for (int off = 1; off < 64; off <<= 1)
            mx = fmaxf(mx, __shfl_xor(mx, off, 64));
        float s = 0.f;
#pragma unroll
        for (int i = 0; i < 16; i++) {
            const float ei = __expf(v[i] - mx);
            v[i] = ei;
            s += ei;
        }
#pragma unroll
        for (int off = 1; off < 64; off <<= 1) s += __shfl_xor(s, off, 64);
        const float inv = 1.f / s;
#pragma unroll
        for (int g = 0; g < 4; g++) {
            ushort4 pk;
            pk.x = f2bf(v[g * 4 + 0] * inv);
            pk.y = f2bf(v[g * 4 + 1] * inv);
            pk.z = f2bf(v[g * 4 + 2] * inv);
            pk.w = f2bf(v[g * 4 + 3] * inv);
            *reinterpret_cast<ushort4*>(
                &P[w * 1024 + ((((lane >> 1) + 32 * g) ^ (w & 7)) << 3) +
                   (lane & 1) * 4]) = pk;
        }
    }
    __syncthreads();

    // ---- Phase 4: PV; wave w -> (kseg = w>>2 of 256 keys, cf = w&3 of 16 d) ----
    const int kseg = w >> 2, cf = w & 3;
    f32x4 pacc = {0.f, 0.f, 0.f, 0.f};
    const unsigned short* vtb =
        vtbf + (size_t)bh * 65536 + (size_t)(cf * 16 + l15) * 1024;
#pragma unroll
    for (int s8 = 0; s8 < 8; s8++) {
        const int kb0 = kseg * 256 + s8 * 32;
        const int g = (kb0 >> 3) + l4;
        const bf16x8 pa = *reinterpret_cast<const bf16x8*>(
            &P[l15 * 1024 + ((g ^ (l15 & 7)) << 3)]);
        const bf16x8 vb = *reinterpret_cast<const bf16x8*>(vtb + kb0 + l4 * 8);
        pacc = __builtin_amdgcn_mfma_f32_16x16x32_bf16(pa, vb, pacc, 0, 0, 0);
    }
    __syncthreads();     // P reads done -> reuse smem for partials
    float* part = smem;  // [4 kseg][16 row][66]
#pragma unroll
    for (int q = 0; q < 4; q++)
        part[kseg * 1056 + (l4 * 4 + q) * 66 + cf * 16 + l15] = pacc[q];
    __syncthreads();
    {
        const float s = part[w * 66 + lane] + part[1056 + w * 66 + lane] +
                        part[2112 + w * 66 + lane] + part[3168 + w * 66 + lane];
        attbf[((size_t)(b * 1024 + n0 + w)) * 512 + h * 64 + lane] = f2bf(s);
    }
}

// ---------------------------------------------------------------------------
extern "C" void kernel_launch(void* const* d_in, const int* in_sizes, int n_in,
                              void* d_out, int out_size, void* d_ws, size_t ws_size,
                              hipStream_t stream) {
    const float* x = (const float*)d_in[0];
    const float* y = (const float*)d_in[1];
    const float* temp = (const float*)d_in[2];
    const float* q_w = (const float*)d_in[3];
    const float* kv_w = (const float*)d_in[4];
    const float* proj_w = (const float*)d_in[5];
    const float* proj_b = (const float*)d_in[6];
    const float* dk_w1 = (const float*)d_in[7];
    const float* dk_b1 = (const float*)d_in[8];
    const float* dk_w2 = (const float*)d_in[9];
    const float* dk_b2 = (const float*)d_in[10];
    const float* ln_g = (const float*)d_in[11];
    const float* ln_b = (const float*)d_in[12];
    float* out = (float*)d_out;
    float* ws = (float*)d_ws;

    float* yp = ws;
    unsigned short* ynbf = (unsigned short*)(ws + 4194304);
    unsigned short* xbf = (unsigned short*)(ws + 6291456);
    unsigned short* qbf = (unsigned short*)(ws + 8388608);
    unsigned short* attbf = (unsigned short*)(ws + 10485760);
    unsigned short* qwbf = (unsigned short*)(ws + 12582912);
    unsigned short* kvwbf = (unsigned short*)(ws + 12713984);
    unsigned short* pwbf = (unsigned short*)(ws + 12976128);
    float* pooled = ws + 13107200;
    int* kvals = (int*)(ws + 13111296);
    unsigned short* kbf = (unsigned short*)ws;               // reuse yp after ln
    unsigned short* vtbf = (unsigned short*)(ws + 2097152);  // reuse yp after ln

    pool_kernel<<<4096, 256, 0, stream>>>(y, yp);
    xtrans<<<4096, 256, 0, stream>>>(x, xbf);
    pooled_kernel<<<4096, 256, 0, stream>>>(x, pooled);
    mlp_kernel<<<8, 128, 0, stream>>>(pooled, dk_w1, dk_b1, dk_w2, dk_b2, kvals);
    convw<<<1024, 256, 0, stream>>>(q_w, kv_w, proj_w, qwbf, kvwbf, pwbf);
    ln_kernel<<<8192, 256, 0, stream>>>(yp, ln_g, ln_b, ynbf);
    gemm_mfma<1><<<dim3(8, 64), 256, 0, stream>>>(ynbf, kvwbf, nullptr, kbf, vtbf, 1024);
    gemm_mfma<0><<<dim3(4, 64), 256, 0, stream>>>(xbf, qwbf, nullptr, qbf, nullptr, 512);
    attn4<<<4096, 1024, 0, stream>>>(qbf, kbf, vtbf, kvals, temp, attbf);
    gemm_mfma<2><<<dim3(4, 64), 256, 0, stream>>>(attbf, pwbf, proj_b, out, nullptr, 512);
}